// Round 2
// baseline (161.655 us; speedup 1.0000x reference)
//
#include <hip/hip_runtime.h>

#define HOURS 24

// Accumulator slots in workspace (doubles):
// 0: sum (yp-yt)^2 over all elements
// 1: sum (yp-yt)^2 over daytime elements
// 2: sum (p_pv - t_pv)^2 over rows
// 3: sum (p_pt - t_pt)^2 over rows
// 4: sum mse_win where valid
// 5: count valid

__global__ __launch_bounds__(256) void peakloss_main(
    const float* __restrict__ ypred, const float* __restrict__ ytrue,
    double* __restrict__ acc, int nrows) {
  float s_sq = 0.f, s_day = 0.f, s_pv = 0.f, s_pt = 0.f, s_shape = 0.f, s_valid = 0.f;

  const int stride = gridDim.x * blockDim.x;
  for (int r = blockIdx.x * blockDim.x + threadIdx.x; r < nrows; r += stride) {
    float t[HOURS], p[HOURS];
    const float4* t4 = (const float4*)(ytrue + (size_t)r * HOURS);
    const float4* p4 = (const float4*)(ypred + (size_t)r * HOURS);
#pragma unroll
    for (int k = 0; k < 6; ++k) {
      float4 a = t4[k];
      t[4 * k + 0] = a.x; t[4 * k + 1] = a.y; t[4 * k + 2] = a.z; t[4 * k + 3] = a.w;
      float4 b = p4[k];
      p[4 * k + 0] = b.x; p[4 * k + 1] = b.y; p[4 * k + 2] = b.z; p[4 * k + 3] = b.w;
    }

    // MSE terms (all compile-time indices -> registers)
#pragma unroll
    for (int h = 0; h < HOURS; ++h) {
      float d = p[h] - t[h];
      float dd = d * d;
      s_sq += dd;
      if (h >= 6 && h <= 20) s_day += dd;
    }

    // daytime max + argmax (first-max semantics, matching jnp.argmax)
    float mt = -1e30f, mp = -1e30f;
    int idx = 6;
#pragma unroll
    for (int h = 6; h <= 20; ++h) {
      if (t[h] > mt) { mt = t[h]; idx = h; }
      mp = fmaxf(mp, p[h]);
    }

    // softmax over daytime hours, T = 0.1  => exp((y - max) * 10)
    float den_t = 0.f, nv_t = 0.f, nt_t = 0.f;
    float den_p = 0.f, nv_p = 0.f, nt_p = 0.f;
#pragma unroll
    for (int h = 6; h <= 20; ++h) {
      float et = __expf((t[h] - mt) * 10.f);
      den_t += et; nv_t += et * t[h]; nt_t += et * (float)h;
      float ep = __expf((p[h] - mp) * 10.f);
      den_p += ep; nv_p += ep * p[h]; nt_p += ep * (float)h;
    }
    float r_t = __builtin_amdgcn_rcpf(den_t);
    float r_p = __builtin_amdgcn_rcpf(den_p);
    float dv = nv_p * r_p - nv_t * r_t;
    float dtm = nt_p * r_p - nt_t * r_t;
    s_pv += dv * dv;
    s_pt += dtm * dtm;

    // peak shape: window [ws, ws+5), ws = idx-2 in [4,18], so h spans [4,22].
    // NO runtime indexing: unroll h with a predicate (keeps t[],p[] in VGPRs).
    int ws = idx - 2;
    float tmax = -1e30f, pmax = -1e30f;
#pragma unroll
    for (int h = 4; h <= 22; ++h) {
      bool in = (h >= ws) & (h < ws + 5);
      if (in) {
        tmax = fmaxf(tmax, t[h]);
        pmax = fmaxf(pmax, p[h]);
      }
    }
    bool valid = tmax > 1e-6f;
    float tms = valid ? tmax : 1.0f;
    float r_tms = __builtin_amdgcn_rcpf(tms);
    float r_pden = __builtin_amdgcn_rcpf(pmax + 1e-6f);
    float a = 0.f;
#pragma unroll
    for (int h = 4; h <= 22; ++h) {
      bool in = (h >= ws) & (h < ws + 5);
      float d = p[h] * r_pden - t[h] * r_tms;
      a += in ? d * d : 0.f;
    }
    if (valid) { s_shape += a * (1.0f / 5.0f); s_valid += 1.0f; }
  }

  // block reduction: wave shuffle, then across 4 waves via LDS, fp64 atomics
  float v[6] = {s_sq, s_day, s_pv, s_pt, s_shape, s_valid};
#pragma unroll
  for (int j = 0; j < 6; ++j) {
#pragma unroll
    for (int off = 32; off >= 1; off >>= 1) v[j] += __shfl_down(v[j], off, 64);
  }
  __shared__ float red[6][4];
  int lane = threadIdx.x & 63, wave = threadIdx.x >> 6;
  if (lane == 0) {
#pragma unroll
    for (int j = 0; j < 6; ++j) red[j][wave] = v[j];
  }
  __syncthreads();
  if (threadIdx.x == 0) {
#pragma unroll
    for (int j = 0; j < 6; ++j) {
      double s = (double)red[j][0] + (double)red[j][1] + (double)red[j][2] + (double)red[j][3];
      atomicAdd(&acc[j], s);
    }
  }
}

__global__ void peakloss_finalize(const double* __restrict__ acc,
                                  float* __restrict__ out,
                                  double inv_BS, double inv_BD) {
  double L_overall = acc[0] * inv_BS;
  double L_day     = acc[1] * inv_BS;          // weighted_mse - L_overall
  double L_pv      = acc[2] * inv_BD;
  double L_pt      = acc[3] * inv_BD;
  double L_shape   = acc[4] / (acc[5] + 1e-6);
  double total = 1.0 * L_overall + 2.0 * L_pv + 1.0 * L_pt + 0.5 * L_shape + 0.5 * L_day;
  out[0] = (float)total;
}

extern "C" void kernel_launch(void* const* d_in, const int* in_sizes, int n_in,
                              void* d_out, int out_size, void* d_ws, size_t ws_size,
                              hipStream_t stream) {
  const float* ypred = (const float*)d_in[0];
  const float* ytrue = (const float*)d_in[1];
  float* out = (float*)d_out;
  double* acc = (double*)d_ws;

  long long N = in_sizes[0];          // B * S
  int nrows = (int)(N / HOURS);       // B * D

  hipMemsetAsync(acc, 0, 6 * sizeof(double), stream);

  int block = 256;
  int grid = (nrows + block - 1) / block;
  if (grid > 2048) grid = 2048;
  peakloss_main<<<grid, block, 0, stream>>>(ypred, ytrue, acc, nrows);

  double inv_BS = 1.0 / (double)N;
  double inv_BD = 1.0 / (double)nrows;
  peakloss_finalize<<<1, 1, 0, stream>>>(acc, out, inv_BS, inv_BD);
}

// Round 3
// 156.339 us; speedup vs baseline: 1.0340x; 1.0340x over previous
//
#include <hip/hip_runtime.h>

#define HOURS 24
#define RPB 256          // rows per block tile
#define PSTR 25          // padded dwords per row in LDS (gcd(25,32)=1 -> conflict-free)

// Accumulator slots (doubles):
// 0: sum (yp-yt)^2 all | 1: sum (yp-yt)^2 daytime | 2: sum (p_pv-t_pv)^2
// 3: sum (p_pt-t_pt)^2 | 4: sum mse_win (valid)   | 5: count valid

__global__ __launch_bounds__(256) void peakloss_main(
    const float* __restrict__ ypred, const float* __restrict__ ytrue,
    double* __restrict__ acc, int nrows) {
  __shared__ float lt[RPB * PSTR];   // 25.6 KB
  __shared__ float lp[RPB * PSTR];   // 25.6 KB

  const int tid = threadIdx.x;
  const int tile0 = blockIdx.x * RPB;
  const int rows = min(RPB, nrows - tile0);

  // ---- stage: coalesced float4 global loads -> padded LDS (b32 scatter) ----
  if (rows == RPB) {
    const float4* t4 = (const float4*)(ytrue + (size_t)tile0 * HOURS);
    const float4* p4 = (const float4*)(ypred + (size_t)tile0 * HOURS);
#pragma unroll
    for (int j = 0; j < 6; ++j) {
      int f4 = tid + j * 256;            // 0..1535, lane-contiguous
      float4 a = t4[f4];
      float4 b = p4[f4];
      int d0 = f4 * 4;
      float av[4] = {a.x, a.y, a.z, a.w};
      float bv[4] = {b.x, b.y, b.z, b.w};
#pragma unroll
      for (int c = 0; c < 4; ++c) {
        int d = d0 + c;
        int pa = d + d / HOURS;          // insert 1 pad dword per 24
        lt[pa] = av[c];
        lp[pa] = bv[c];
      }
    }
  } else {
    for (int d = tid; d < rows * HOURS; d += 256) {
      int pa = d + d / HOURS;
      lt[pa] = ytrue[(size_t)tile0 * HOURS + d];
      lp[pa] = ypred[(size_t)tile0 * HOURS + d];
    }
  }
  __syncthreads();

  float s_sq = 0.f, s_day = 0.f, s_pv = 0.f, s_pt = 0.f, s_shape = 0.f, s_valid = 0.f;

  if (tid < rows) {
    const float* tr = lt + tid * PSTR;
    const float* pr = lp + tid * PSTR;

    // ---- pass 1: mse sums + daytime max/argmax (first-max semantics) ----
    float mt = -1e30f, mp = -1e30f;
    int idx = 6;
#pragma unroll
    for (int h = 0; h < HOURS; ++h) {
      float th = tr[h], ph = pr[h];
      float d = ph - th;
      float dd = d * d;
      s_sq += dd;
      if (h >= 6 && h <= 20) {
        s_day += dd;
        if (th > mt) { mt = th; idx = h; }
        mp = fmaxf(mp, ph);
      }
    }

    // ---- pass 2: softmax sums (T=0.1) + window maxima ----
    int ws = idx - 2;                    // in [4,18]; window [ws, ws+5) in [4,23)
    float den_t = 0.f, nv_t = 0.f, nt_t = 0.f;
    float den_p = 0.f, nv_p = 0.f, nt_p = 0.f;
    float tmax = -1e30f, pmax = -1e30f;
#pragma unroll
    for (int h = 4; h <= 22; ++h) {
      float th = tr[h], ph = pr[h];
      if (h >= 6 && h <= 20) {
        float et = __expf((th - mt) * 10.f);
        den_t += et; nv_t += et * th; nt_t += et * (float)h;
        float ep = __expf((ph - mp) * 10.f);
        den_p += ep; nv_p += ep * ph; nt_p += ep * (float)h;
      }
      bool in = (h >= ws) & (h < ws + 5);
      if (in) { tmax = fmaxf(tmax, th); pmax = fmaxf(pmax, ph); }
    }
    float r_t = __builtin_amdgcn_rcpf(den_t);
    float r_p = __builtin_amdgcn_rcpf(den_p);
    float dv  = nv_p * r_p - nv_t * r_t;
    float dtm = nt_p * r_p - nt_t * r_t;
    s_pv += dv * dv;
    s_pt += dtm * dtm;

    // ---- pass 3: windowed normalized shape mse ----
    bool valid = tmax > 1e-6f;
    float tms = valid ? tmax : 1.0f;
    float r_tms  = __builtin_amdgcn_rcpf(tms);
    float r_pden = __builtin_amdgcn_rcpf(pmax + 1e-6f);
    float a = 0.f;
#pragma unroll
    for (int h = 4; h <= 22; ++h) {
      bool in = (h >= ws) & (h < ws + 5);
      float d = pr[h] * r_pden - tr[h] * r_tms;
      a += in ? d * d : 0.f;
    }
    if (valid) { s_shape += a * 0.2f; s_valid += 1.0f; }
  }

  // ---- block reduction: wave shuffle -> LDS across 4 waves -> fp64 atomics ----
  float v[6] = {s_sq, s_day, s_pv, s_pt, s_shape, s_valid};
#pragma unroll
  for (int j = 0; j < 6; ++j) {
#pragma unroll
    for (int off = 32; off >= 1; off >>= 1) v[j] += __shfl_down(v[j], off, 64);
  }
  __shared__ float red[6][4];
  int lane = threadIdx.x & 63, wave = threadIdx.x >> 6;
  __syncthreads();
  if (lane == 0) {
#pragma unroll
    for (int j = 0; j < 6; ++j) red[j][wave] = v[j];
  }
  __syncthreads();
  if (threadIdx.x == 0) {
#pragma unroll
    for (int j = 0; j < 6; ++j) {
      double s = (double)red[j][0] + (double)red[j][1] + (double)red[j][2] + (double)red[j][3];
      atomicAdd(&acc[j], s);
    }
  }
}

__global__ void peakloss_finalize(const double* __restrict__ acc,
                                  float* __restrict__ out,
                                  double inv_BS, double inv_BD) {
  double L_overall = acc[0] * inv_BS;
  double L_day     = acc[1] * inv_BS;          // weighted_mse - L_overall
  double L_pv      = acc[2] * inv_BD;
  double L_pt      = acc[3] * inv_BD;
  double L_shape   = acc[4] / (acc[5] + 1e-6);
  double total = 1.0 * L_overall + 2.0 * L_pv + 1.0 * L_pt + 0.5 * L_shape + 0.5 * L_day;
  out[0] = (float)total;
}

extern "C" void kernel_launch(void* const* d_in, const int* in_sizes, int n_in,
                              void* d_out, int out_size, void* d_ws, size_t ws_size,
                              hipStream_t stream) {
  const float* ypred = (const float*)d_in[0];
  const float* ytrue = (const float*)d_in[1];
  float* out = (float*)d_out;
  double* acc = (double*)d_ws;

  long long N = in_sizes[0];          // B * S
  int nrows = (int)(N / HOURS);       // B * D

  hipMemsetAsync(acc, 0, 6 * sizeof(double), stream);

  int grid = (nrows + RPB - 1) / RPB;
  peakloss_main<<<grid, 256, 0, stream>>>(ypred, ytrue, acc, nrows);

  double inv_BS = 1.0 / (double)N;
  double inv_BD = 1.0 / (double)nrows;
  peakloss_finalize<<<1, 1, 0, stream>>>(acc, out, inv_BS, inv_BD);
}

// Round 4
// 26.709 us; speedup vs baseline: 6.0525x; 5.8535x over previous
//
#include <hip/hip_runtime.h>

#define HOURS 24
#define RPB 256          // rows per block tile
#define PSTR 25          // padded dwords per row in LDS (gcd(25,32)=1 -> conflict-free)
#define NBLK 1920        // 491520 rows / 256  (general path still handles any size)

// Workspace layout: float partials[6][num_blocks]
// 0: sum (yp-yt)^2 all | 1: sum (yp-yt)^2 daytime | 2: sum (p_pv-t_pv)^2
// 3: sum (p_pt-t_pt)^2 | 4: sum mse_win (valid)   | 5: count valid

__global__ __launch_bounds__(256) void peakloss_main(
    const float* __restrict__ ypred, const float* __restrict__ ytrue,
    float* __restrict__ partials, int nrows, int nblocks) {
  __shared__ float lt[RPB * PSTR];   // 25.6 KB
  __shared__ float lp[RPB * PSTR];   // 25.6 KB

  const int tid = threadIdx.x;
  const int tile0 = blockIdx.x * RPB;
  const int rows = min(RPB, nrows - tile0);

  // ---- stage: coalesced float4 global loads -> padded LDS (b32 scatter) ----
  if (rows == RPB) {
    const float4* t4 = (const float4*)(ytrue + (size_t)tile0 * HOURS);
    const float4* p4 = (const float4*)(ypred + (size_t)tile0 * HOURS);
#pragma unroll
    for (int j = 0; j < 6; ++j) {
      int f4 = tid + j * 256;            // 0..1535, lane-contiguous
      float4 a = t4[f4];
      float4 b = p4[f4];
      int d0 = f4 * 4;
      float av[4] = {a.x, a.y, a.z, a.w};
      float bv[4] = {b.x, b.y, b.z, b.w};
#pragma unroll
      for (int c = 0; c < 4; ++c) {
        int d = d0 + c;
        int pa = d + d / HOURS;          // insert 1 pad dword per 24
        lt[pa] = av[c];
        lp[pa] = bv[c];
      }
    }
  } else {
    for (int d = tid; d < rows * HOURS; d += 256) {
      int pa = d + d / HOURS;
      lt[pa] = ytrue[(size_t)tile0 * HOURS + d];
      lp[pa] = ypred[(size_t)tile0 * HOURS + d];
    }
  }
  __syncthreads();

  float s_sq = 0.f, s_day = 0.f, s_pv = 0.f, s_pt = 0.f, s_shape = 0.f, s_valid = 0.f;

  if (tid < rows) {
    const float* tr = lt + tid * PSTR;
    const float* pr = lp + tid * PSTR;

    // ---- pass 1: mse sums + daytime max/argmax (first-max semantics) ----
    float mt = -1e30f, mp = -1e30f;
    int idx = 6;
#pragma unroll
    for (int h = 0; h < HOURS; ++h) {
      float th = tr[h], ph = pr[h];
      float d = ph - th;
      float dd = d * d;
      s_sq += dd;
      if (h >= 6 && h <= 20) {
        s_day += dd;
        if (th > mt) { mt = th; idx = h; }
        mp = fmaxf(mp, ph);
      }
    }

    // ---- pass 2: softmax sums (T=0.1) + window maxima ----
    int ws = idx - 2;                    // in [4,18]; window [ws, ws+5) in [4,23)
    float den_t = 0.f, nv_t = 0.f, nt_t = 0.f;
    float den_p = 0.f, nv_p = 0.f, nt_p = 0.f;
    float tmax = -1e30f, pmax = -1e30f;
#pragma unroll
    for (int h = 4; h <= 22; ++h) {
      float th = tr[h], ph = pr[h];
      if (h >= 6 && h <= 20) {
        float et = __expf((th - mt) * 10.f);
        den_t += et; nv_t += et * th; nt_t += et * (float)h;
        float ep = __expf((ph - mp) * 10.f);
        den_p += ep; nv_p += ep * ph; nt_p += ep * (float)h;
      }
      bool in = (h >= ws) & (h < ws + 5);
      if (in) { tmax = fmaxf(tmax, th); pmax = fmaxf(pmax, ph); }
    }
    float r_t = __builtin_amdgcn_rcpf(den_t);
    float r_p = __builtin_amdgcn_rcpf(den_p);
    float dv  = nv_p * r_p - nv_t * r_t;
    float dtm = nt_p * r_p - nt_t * r_t;
    s_pv += dv * dv;
    s_pt += dtm * dtm;

    // ---- pass 3: windowed normalized shape mse ----
    bool valid = tmax > 1e-6f;
    float tms = valid ? tmax : 1.0f;
    float r_tms  = __builtin_amdgcn_rcpf(tms);
    float r_pden = __builtin_amdgcn_rcpf(pmax + 1e-6f);
    float a = 0.f;
#pragma unroll
    for (int h = 4; h <= 22; ++h) {
      bool in = (h >= ws) & (h < ws + 5);
      float d = pr[h] * r_pden - tr[h] * r_tms;
      a += in ? d * d : 0.f;
    }
    if (valid) { s_shape += a * 0.2f; s_valid += 1.0f; }
  }

  // ---- block reduction: wave shuffle -> LDS across 4 waves -> per-block write ----
  float v[6] = {s_sq, s_day, s_pv, s_pt, s_shape, s_valid};
#pragma unroll
  for (int j = 0; j < 6; ++j) {
#pragma unroll
    for (int off = 32; off >= 1; off >>= 1) v[j] += __shfl_down(v[j], off, 64);
  }
  __shared__ float red[6][4];
  int lane = threadIdx.x & 63, wave = threadIdx.x >> 6;
  __syncthreads();
  if (lane == 0) {
#pragma unroll
    for (int j = 0; j < 6; ++j) red[j][wave] = v[j];
  }
  __syncthreads();
  if (threadIdx.x < 6) {
    int j = threadIdx.x;
    partials[(size_t)j * nblocks + blockIdx.x] =
        red[j][0] + red[j][1] + red[j][2] + red[j][3];
  }
}

// Single-block final reduction in fp64; writes the scalar loss.
__global__ __launch_bounds__(256) void peakloss_reduce(
    const float* __restrict__ partials, float* __restrict__ out,
    int nblocks, double inv_BS, double inv_BD) {
  double s[6] = {0, 0, 0, 0, 0, 0};
  for (int i = threadIdx.x; i < nblocks; i += 256) {
#pragma unroll
    for (int j = 0; j < 6; ++j) s[j] += (double)partials[(size_t)j * nblocks + i];
  }
#pragma unroll
  for (int j = 0; j < 6; ++j) {
#pragma unroll
    for (int off = 32; off >= 1; off >>= 1) s[j] += __shfl_down(s[j], off, 64);
  }
  __shared__ double red[6][4];
  int lane = threadIdx.x & 63, wave = threadIdx.x >> 6;
  if (lane == 0) {
#pragma unroll
    for (int j = 0; j < 6; ++j) red[j][wave] = s[j];
  }
  __syncthreads();
  if (threadIdx.x == 0) {
    double a[6];
#pragma unroll
    for (int j = 0; j < 6; ++j)
      a[j] = red[j][0] + red[j][1] + red[j][2] + red[j][3];
    double L_overall = a[0] * inv_BS;
    double L_day     = a[1] * inv_BS;          // weighted_mse - L_overall
    double L_pv      = a[2] * inv_BD;
    double L_pt      = a[3] * inv_BD;
    double L_shape   = a[4] / (a[5] + 1e-6);
    out[0] = (float)(L_overall + 2.0 * L_pv + L_pt + 0.5 * L_shape + 0.5 * L_day);
  }
}

extern "C" void kernel_launch(void* const* d_in, const int* in_sizes, int n_in,
                              void* d_out, int out_size, void* d_ws, size_t ws_size,
                              hipStream_t stream) {
  const float* ypred = (const float*)d_in[0];
  const float* ytrue = (const float*)d_in[1];
  float* out = (float*)d_out;
  float* partials = (float*)d_ws;

  long long N = in_sizes[0];          // B * S
  int nrows = (int)(N / HOURS);       // B * D
  int grid = (nrows + RPB - 1) / RPB; // 1920 for the bench shape

  peakloss_main<<<grid, 256, 0, stream>>>(ypred, ytrue, partials, nrows, grid);

  double inv_BS = 1.0 / (double)N;
  double inv_BD = 1.0 / (double)nrows;
  peakloss_reduce<<<1, 256, 0, stream>>>(partials, out, grid, inv_BS, inv_BD);
}